// Round 8
// baseline (58.425 us; speedup 1.0000x reference)
//
#include <hip/hip_runtime.h>
#include <math.h>

// Problem constants (B=4, C=64, H=W=512, s=2 -> quadrant tiles of 256x256)
#define HH 512
#define WW 512
#define HW (HH * WW)          // 262144 = 2^18
#define CCH 64
#define BB 4

typedef float    f4 __attribute__((ext_vector_type(4)));
typedef _Float16 h2 __attribute__((ext_vector_type(2)));
typedef _Float16 h8 __attribute__((ext_vector_type(8)));

// ---------------------------------------------------------------------------
// Kernel 1: per-pixel channel reduction, 8 px/thread (2x float4 per channel
// -> 2 KB contiguous per wave per channel visit, doubling DRAM row-hit
// locality vs 4 px), 512 blocks (8 waves/CU). Channel start staggered by
// block (8 phases) so concurrent blocks don't hammer the same channel plane
// in lockstep (1 MiB power-of-2 stride = row/bank thrash when synchronized).
// Outputs fp16: l2 plane (2 B/px) + interleaved (max,mean) plane (4 B/px).
// ---------------------------------------------------------------------------
__global__ __launch_bounds__(256) void reduce_k(const float* __restrict__ x,
                                                _Float16* __restrict__ l2p,
                                                h2* __restrict__ mmp) {
    int tid = blockIdx.x * 256 + threadIdx.x;      // 0 .. B*HW/8 - 1
    int b  = tid >> 15;                            // HW/8 = 32768
    int p8 = tid & 32767;

    const f4* xb = reinterpret_cast<const f4*>(x)
                 + (size_t)b * CCH * (HW / 4) + (size_t)p8 * 2;

    f4 ss0 = {0.f, 0.f, 0.f, 0.f}, ss1 = ss0;
    f4 sm0 = ss0, sm1 = ss0;
    f4 mx0 = {-INFINITY, -INFINITY, -INFINITY, -INFINITY}, mx1 = mx0;

#define RED_BODY(c)                                                   \
    {                                                                 \
        const f4* p = xb + (size_t)(c) * (HW / 4);                    \
        f4 v0 = p[0];                                                 \
        f4 v1 = p[1];                                                 \
        ss0 += v0 * v0;  ss1 += v1 * v1;                              \
        sm0 += v0;       sm1 += v1;                                   \
        mx0.x = fmaxf(mx0.x, v0.x); mx0.y = fmaxf(mx0.y, v0.y);       \
        mx0.z = fmaxf(mx0.z, v0.z); mx0.w = fmaxf(mx0.w, v0.w);       \
        mx1.x = fmaxf(mx1.x, v1.x); mx1.y = fmaxf(mx1.y, v1.y);       \
        mx1.z = fmaxf(mx1.z, v1.z); mx1.w = fmaxf(mx1.w, v1.w);       \
    }

    int c0 = (blockIdx.x & 7) * 8;   // 8 stagger phases, trip counts %8==0
#pragma unroll 8
    for (int c = c0; c < CCH; ++c) RED_BODY(c)
#pragma unroll 8
    for (int c = 0; c < c0; ++c) RED_BODY(c)
#undef RED_BODY

    const float inv = 1.0f / 64.0f;
    h8 mmA = { (_Float16)mx0.x, (_Float16)(sm0.x * inv),
               (_Float16)mx0.y, (_Float16)(sm0.y * inv),
               (_Float16)mx0.z, (_Float16)(sm0.z * inv),
               (_Float16)mx0.w, (_Float16)(sm0.w * inv) };
    h8 mmB = { (_Float16)mx1.x, (_Float16)(sm1.x * inv),
               (_Float16)mx1.y, (_Float16)(sm1.y * inv),
               (_Float16)mx1.z, (_Float16)(sm1.z * inv),
               (_Float16)mx1.w, (_Float16)(sm1.w * inv) };
    h8 l2v = { (_Float16)sqrtf(ss0.x), (_Float16)sqrtf(ss0.y),
               (_Float16)sqrtf(ss0.z), (_Float16)sqrtf(ss0.w),
               (_Float16)sqrtf(ss1.x), (_Float16)sqrtf(ss1.y),
               (_Float16)sqrtf(ss1.z), (_Float16)sqrtf(ss1.w) };

    size_t o8 = (size_t)b * (HW / 8) + p8;
    reinterpret_cast<h8*>(mmp)[o8 * 2]     = mmA;   // 16 B
    reinterpret_cast<h8*>(mmp)[o8 * 2 + 1] = mmB;   // 16 B
    reinterpret_cast<h8*>(l2p)[o8]         = l2v;   // 16 B
}

// ---------------------------------------------------------------------------
// Kernel 2: both attention branches + sum, 8 consecutive output px/thread.
// Per conv row: h8 vector loads + 2 guarded edge scalars, reused across the
// 8 outputs. fp16 inputs; fp32 accumulate. NT output stores.
//
// local path index math (raw row-major reshape [B,4,256,256] -> [B,1,512,512]):
//   c = h>>7 ; hs = ((h&127)<<1)|(w>>8) ; ws = w&255
// tiles[b,i,y,x] = l2[b, (i>>1)*256 + y, (i&1)*256 + x], zero-padded in TILE
// space (guards on tile coords, NOT image coords). For 8-aligned w0, both
// hs and the ws run (ws0..ws0+7) stay within one quadrant row segment.
// ---------------------------------------------------------------------------
__global__ __launch_bounds__(256) void attn_k(const _Float16* __restrict__ l2p,
                                              const h2* __restrict__ mmp,
                                              const float* __restrict__ lw,
                                              const float* __restrict__ lb,
                                              const float* __restrict__ gw,
                                              const float* __restrict__ gb,
                                              float* __restrict__ out) {
    __shared__ float s_lw[144];   // [4,4,3,3]
    __shared__ float s_lb[4];
    __shared__ float s_gw[18];    // [1,2,3,3]
    __shared__ float s_gb;

    int t = threadIdx.x;
    if (t < 144) s_lw[t] = lw[t];
    if (t < 4)   s_lb[t] = lb[t];
    if (t < 18)  s_gw[t] = gw[t];
    if (t == 0)  s_gb = gb[0];
    __syncthreads();

    int idx8 = blockIdx.x * 256 + t;   // 0 .. B*HW/8 - 1
    int b  = idx8 >> 15;               // HW/8 = 32768
    int p8 = idx8 & 32767;
    int h  = p8 >> 6;                  // 64 chunks of 8 px per row
    int w0 = (p8 & 63) << 3;           // 0..504, multiple of 8

    const _Float16* l2b = l2p + ((size_t)b << 18);
    const h2*       mmb = mmp + ((size_t)b << 18);

    // ---- global attention: 3x3 conv over (max, mean), relu, sigmoid ----
    float g[8];
#pragma unroll
    for (int j = 0; j < 8; ++j) g[j] = s_gb;
#pragma unroll
    for (int dh = -1; dh <= 1; ++dh) {
        int hh = h + dh;
        if ((unsigned)hh >= (unsigned)HH) continue;
        const h2* row = mmb + hh * WW + w0;
        h8 vA = *reinterpret_cast<const h8*>(row);       // px w0..w0+3
        h8 vB = *reinterpret_cast<const h8*>(row + 4);   // px w0+4..w0+7
        float m10[10], a10[10];
        if (w0 > 0) { h2 e = row[-1]; m10[0] = (float)e.x; a10[0] = (float)e.y; }
        else        { m10[0] = 0.f;   a10[0] = 0.f; }
#pragma unroll
        for (int j = 0; j < 4; ++j) {
            m10[1 + j] = (float)vA[2 * j];  a10[1 + j] = (float)vA[2 * j + 1];
            m10[5 + j] = (float)vB[2 * j];  a10[5 + j] = (float)vB[2 * j + 1];
        }
        if (w0 < WW - 8) { h2 e = row[8]; m10[9] = (float)e.x; a10[9] = (float)e.y; }
        else             { m10[9] = 0.f;  a10[9] = 0.f; }
#pragma unroll
        for (int k = 0; k < 3; ++k) {
            float wmk = s_gw[(dh + 1) * 3 + k];
            float wak = s_gw[9 + (dh + 1) * 3 + k];
#pragma unroll
            for (int j = 0; j < 8; ++j)
                g[j] = fmaf(m10[j + k], wmk, fmaf(a10[j + k], wak, g[j]));
        }
    }

    // ---- local attention: 3x3 conv (4 quadrant in-ch) in tile space ----
    int c   = h >> 7;
    int hs  = ((h & 127) << 1) | (w0 >> 8);
    int ws0 = w0 & 255;                // multiple of 8, 0..248

    float la[8];
#pragma unroll
    for (int j = 0; j < 8; ++j) la[j] = s_lb[c];
#pragma unroll
    for (int i = 0; i < 4; ++i) {
        const _Float16* base = l2b + (i >> 1) * (256 * WW) + (i & 1) * 256;
        const float* wi = s_lw + c * 36 + i * 9;
#pragma unroll
        for (int dh = -1; dh <= 1; ++dh) {
            int y = hs + dh;
            if ((unsigned)y >= 256u) continue;
            const _Float16* row = base + y * WW + ws0;
            h8 v = *reinterpret_cast<const h8*>(row);    // 16 B aligned
            float v10[10];
            v10[0] = (ws0 > 0)   ? (float)row[-1] : 0.f;
#pragma unroll
            for (int j = 0; j < 8; ++j) v10[1 + j] = (float)v[j];
            v10[9] = (ws0 < 248) ? (float)row[8]  : 0.f;
#pragma unroll
            for (int k = 0; k < 3; ++k) {
                float wk = wi[(dh + 1) * 3 + k];
#pragma unroll
                for (int j = 0; j < 8; ++j)
                    la[j] = fmaf(v10[j + k], wk, la[j]);
            }
        }
    }

    f4 oA, oB;
#pragma unroll
    for (int j = 0; j < 4; ++j) {
        oA[j] = 1.f / (1.f + __expf(-la[j]))
              + 1.f / (1.f + __expf(-fmaxf(g[j], 0.f)));
        oB[j] = 1.f / (1.f + __expf(-la[4 + j]))
              + 1.f / (1.f + __expf(-fmaxf(g[4 + j], 0.f)));
    }
    __builtin_nontemporal_store(oA, reinterpret_cast<f4*>(out) + idx8 * 2);
    __builtin_nontemporal_store(oB, reinterpret_cast<f4*>(out) + idx8 * 2 + 1);
}

extern "C" void kernel_launch(void* const* d_in, const int* in_sizes, int n_in,
                              void* d_out, int out_size, void* d_ws, size_t ws_size,
                              hipStream_t stream) {
    const float* x  = (const float*)d_in[0];   // [4,64,512,512]
    const float* lw = (const float*)d_in[1];   // [4,4,3,3]
    const float* lb = (const float*)d_in[2];   // [4]
    const float* gw = (const float*)d_in[3];   // [1,2,3,3]
    const float* gb = (const float*)d_in[4];   // [1]
    float* out = (float*)d_out;                // [4,1,512,512]

    h2*       mmp = (h2*)d_ws;                           // 4 MiB (max,mean)/px
    _Float16* l2p = (_Float16*)((char*)d_ws + (size_t)BB * HW * sizeof(h2));

    int n1 = BB * HW / 8;                      // 131072 threads, 8 px each
    reduce_k<<<n1 / 256, 256, 0, stream>>>(x, l2p, mmp);

    int n2 = BB * HW / 8;                      // 131072 threads, 8 px each
    attn_k<<<n2 / 256, 256, 0, stream>>>(l2p, mmp, lw, lb, gw, gb, out);
}

// Round 9
// 56.895 us; speedup vs baseline: 1.0269x; 1.0269x over previous
//
#include <hip/hip_runtime.h>
#include <math.h>

// Problem constants (B=4, C=64, H=W=512, s=2 -> quadrant tiles of 256x256)
#define HH 512
#define WW 512
#define HW (HH * WW)          // 262144 = 2^18
#define CCH 64
#define BB 4

typedef float    f4 __attribute__((ext_vector_type(4)));
typedef _Float16 h2 __attribute__((ext_vector_type(2)));
typedef _Float16 h4 __attribute__((ext_vector_type(4)));
typedef _Float16 h8 __attribute__((ext_vector_type(8)));

// ---------------------------------------------------------------------------
// Kernel 1: per-pixel channel reduction, 4 px/thread (float4), 2048 blocks
// = 32 waves/CU (MAX occupancy; launch_bounds(256,8) caps VGPR <= 64).
// Theory: the poison-fill kernels hit 7 TB/s at VGPR=8/max-occupancy; our
// k1 plateaued at ~5.2 TB/s with only 8-16 waves/CU. For a mixed
// LLC-hit/HBM-miss read stream, raise memory-level parallelism to cover
// the miss latency. Plain ascending channel loop (stagger was neutral).
// Outputs fp16: l2 plane (2 B/px) + interleaved (max,mean) plane (4 B/px).
// ---------------------------------------------------------------------------
__global__ __launch_bounds__(256, 8) void reduce_k(const float* __restrict__ x,
                                                   _Float16* __restrict__ l2p,
                                                   h2* __restrict__ mmp) {
    int tid = blockIdx.x * 256 + threadIdx.x;      // 0 .. B*HW/4 - 1
    int b  = tid >> 16;                            // HW/4 = 65536
    int p4 = tid & 65535;

    const f4* xb = reinterpret_cast<const f4*>(x)
                 + (size_t)b * CCH * (HW / 4) + p4;

    f4 ss = {0.f, 0.f, 0.f, 0.f};
    f4 sm = {0.f, 0.f, 0.f, 0.f};
    f4 mx = {-INFINITY, -INFINITY, -INFINITY, -INFINITY};

#pragma unroll 8
    for (int c = 0; c < CCH; ++c) {
        f4 v = xb[(size_t)c * (HW / 4)];
        ss += v * v;
        sm += v;
        mx.x = fmaxf(mx.x, v.x);
        mx.y = fmaxf(mx.y, v.y);
        mx.z = fmaxf(mx.z, v.z);
        mx.w = fmaxf(mx.w, v.w);
    }

    size_t o4 = (size_t)b * (HW / 4) + p4;
    const float inv = 1.0f / 64.0f;
    h8 mm = { (_Float16)mx.x, (_Float16)(sm.x * inv),
              (_Float16)mx.y, (_Float16)(sm.y * inv),
              (_Float16)mx.z, (_Float16)(sm.z * inv),
              (_Float16)mx.w, (_Float16)(sm.w * inv) };
    h4 l2v = { (_Float16)sqrtf(ss.x), (_Float16)sqrtf(ss.y),
               (_Float16)sqrtf(ss.z), (_Float16)sqrtf(ss.w) };
    reinterpret_cast<h8*>(mmp)[o4] = mm;           // 16 B store
    reinterpret_cast<h4*>(l2p)[o4] = l2v;          // 8 B store
}

// ---------------------------------------------------------------------------
// Kernel 2 (unchanged from R8): both branches + sum, 8 px/thread.
// Per conv row: h8 vector loads + 2 guarded edge scalars, reused across the
// 8 outputs. fp16 inputs; fp32 accumulate. NT output stores.
//
// local path index math (raw row-major reshape [B,4,256,256] -> [B,1,512,512]):
//   c = h>>7 ; hs = ((h&127)<<1)|(w>>8) ; ws = w&255
// tiles[b,i,y,x] = l2[b, (i>>1)*256 + y, (i&1)*256 + x], zero-padded in TILE
// space (guards on tile coords, NOT image coords).
// ---------------------------------------------------------------------------
__global__ __launch_bounds__(256) void attn_k(const _Float16* __restrict__ l2p,
                                              const h2* __restrict__ mmp,
                                              const float* __restrict__ lw,
                                              const float* __restrict__ lb,
                                              const float* __restrict__ gw,
                                              const float* __restrict__ gb,
                                              float* __restrict__ out) {
    __shared__ float s_lw[144];   // [4,4,3,3]
    __shared__ float s_lb[4];
    __shared__ float s_gw[18];    // [1,2,3,3]
    __shared__ float s_gb;

    int t = threadIdx.x;
    if (t < 144) s_lw[t] = lw[t];
    if (t < 4)   s_lb[t] = lb[t];
    if (t < 18)  s_gw[t] = gw[t];
    if (t == 0)  s_gb = gb[0];
    __syncthreads();

    int idx8 = blockIdx.x * 256 + t;   // 0 .. B*HW/8 - 1
    int b  = idx8 >> 15;               // HW/8 = 32768
    int p8 = idx8 & 32767;
    int h  = p8 >> 6;                  // 64 chunks of 8 px per row
    int w0 = (p8 & 63) << 3;           // 0..504, multiple of 8

    const _Float16* l2b = l2p + ((size_t)b << 18);
    const h2*       mmb = mmp + ((size_t)b << 18);

    // ---- global attention: 3x3 conv over (max, mean), relu, sigmoid ----
    float g[8];
#pragma unroll
    for (int j = 0; j < 8; ++j) g[j] = s_gb;
#pragma unroll
    for (int dh = -1; dh <= 1; ++dh) {
        int hh = h + dh;
        if ((unsigned)hh >= (unsigned)HH) continue;
        const h2* row = mmb + hh * WW + w0;
        h8 vA = *reinterpret_cast<const h8*>(row);       // px w0..w0+3
        h8 vB = *reinterpret_cast<const h8*>(row + 4);   // px w0+4..w0+7
        float m10[10], a10[10];
        if (w0 > 0) { h2 e = row[-1]; m10[0] = (float)e.x; a10[0] = (float)e.y; }
        else        { m10[0] = 0.f;   a10[0] = 0.f; }
#pragma unroll
        for (int j = 0; j < 4; ++j) {
            m10[1 + j] = (float)vA[2 * j];  a10[1 + j] = (float)vA[2 * j + 1];
            m10[5 + j] = (float)vB[2 * j];  a10[5 + j] = (float)vB[2 * j + 1];
        }
        if (w0 < WW - 8) { h2 e = row[8]; m10[9] = (float)e.x; a10[9] = (float)e.y; }
        else             { m10[9] = 0.f;  a10[9] = 0.f; }
#pragma unroll
        for (int k = 0; k < 3; ++k) {
            float wmk = s_gw[(dh + 1) * 3 + k];
            float wak = s_gw[9 + (dh + 1) * 3 + k];
#pragma unroll
            for (int j = 0; j < 8; ++j)
                g[j] = fmaf(m10[j + k], wmk, fmaf(a10[j + k], wak, g[j]));
        }
    }

    // ---- local attention: 3x3 conv (4 quadrant in-ch) in tile space ----
    int c   = h >> 7;
    int hs  = ((h & 127) << 1) | (w0 >> 8);
    int ws0 = w0 & 255;                // multiple of 8, 0..248

    float la[8];
#pragma unroll
    for (int j = 0; j < 8; ++j) la[j] = s_lb[c];
#pragma unroll
    for (int i = 0; i < 4; ++i) {
        const _Float16* base = l2b + (i >> 1) * (256 * WW) + (i & 1) * 256;
        const float* wi = s_lw + c * 36 + i * 9;
#pragma unroll
        for (int dh = -1; dh <= 1; ++dh) {
            int y = hs + dh;
            if ((unsigned)y >= 256u) continue;
            const _Float16* row = base + y * WW + ws0;
            h8 v = *reinterpret_cast<const h8*>(row);    // 16 B aligned
            float v10[10];
            v10[0] = (ws0 > 0)   ? (float)row[-1] : 0.f;
#pragma unroll
            for (int j = 0; j < 8; ++j) v10[1 + j] = (float)v[j];
            v10[9] = (ws0 < 248) ? (float)row[8]  : 0.f;
#pragma unroll
            for (int k = 0; k < 3; ++k) {
                float wk = wi[(dh + 1) * 3 + k];
#pragma unroll
                for (int j = 0; j < 8; ++j)
                    la[j] = fmaf(v10[j + k], wk, la[j]);
            }
        }
    }

    f4 oA, oB;
#pragma unroll
    for (int j = 0; j < 4; ++j) {
        oA[j] = 1.f / (1.f + __expf(-la[j]))
              + 1.f / (1.f + __expf(-fmaxf(g[j], 0.f)));
        oB[j] = 1.f / (1.f + __expf(-la[4 + j]))
              + 1.f / (1.f + __expf(-fmaxf(g[4 + j], 0.f)));
    }
    __builtin_nontemporal_store(oA, reinterpret_cast<f4*>(out) + idx8 * 2);
    __builtin_nontemporal_store(oB, reinterpret_cast<f4*>(out) + idx8 * 2 + 1);
}

extern "C" void kernel_launch(void* const* d_in, const int* in_sizes, int n_in,
                              void* d_out, int out_size, void* d_ws, size_t ws_size,
                              hipStream_t stream) {
    const float* x  = (const float*)d_in[0];   // [4,64,512,512]
    const float* lw = (const float*)d_in[1];   // [4,4,3,3]
    const float* lb = (const float*)d_in[2];   // [4]
    const float* gw = (const float*)d_in[3];   // [1,2,3,3]
    const float* gb = (const float*)d_in[4];   // [1]
    float* out = (float*)d_out;                // [4,1,512,512]

    h2*       mmp = (h2*)d_ws;                           // 4 MiB (max,mean)/px
    _Float16* l2p = (_Float16*)((char*)d_ws + (size_t)BB * HW * sizeof(h2));

    int n1 = BB * HW / 4;                      // 262144 threads, 4 px each
    reduce_k<<<n1 / 256, 256, 0, stream>>>(x, l2p, mmp);   // 2048 blocks

    int n2 = BB * HW / 8;                      // 131072 threads, 8 px each
    attn_k<<<n2 / 256, 256, 0, stream>>>(l2p, mmp, lw, lb, gw, gb, out);
}

// Round 10
// 56.828 us; speedup vs baseline: 1.0281x; 1.0012x over previous
//
#include <hip/hip_runtime.h>
#include <math.h>

// Problem constants (B=4, C=64, H=W=512, s=2 -> quadrant tiles of 256x256)
#define HH 512
#define WW 512
#define HW (HH * WW)          // 262144 = 2^18
#define CCH 64
#define BB 4

typedef float    f2 __attribute__((ext_vector_type(2)));
typedef float    f4 __attribute__((ext_vector_type(4)));
typedef _Float16 h2 __attribute__((ext_vector_type(2)));
typedef _Float16 h4 __attribute__((ext_vector_type(4)));
typedef _Float16 h8 __attribute__((ext_vector_type(8)));

// ---------------------------------------------------------------------------
// Kernel 1: per-pixel channel reduction, 2 px/thread (float2), 2048 blocks
// = TRUE 32 waves/CU max occupancy (R9's grid was 1024 blocks = 16 w/CU;
// the VGPR cap alone gave +1.5us; this doubles resident waves, matching
// the 7 TB/s fill kernels' shape: tiny VGPR + max waves). 512 B contiguous
// per wave-load, fully coalesced. Outputs fp16 planes.
// ---------------------------------------------------------------------------
__global__ __launch_bounds__(256, 8) void reduce_k(const float* __restrict__ x,
                                                   _Float16* __restrict__ l2p,
                                                   h2* __restrict__ mmp) {
    int tid = blockIdx.x * 256 + threadIdx.x;      // 0 .. B*HW/2 - 1
    int b  = tid >> 17;                            // HW/2 = 131072
    int p2 = tid & 131071;

    const f2* xb = reinterpret_cast<const f2*>(x)
                 + (size_t)b * CCH * (HW / 2) + p2;

    f2 ss = {0.f, 0.f};
    f2 sm = {0.f, 0.f};
    f2 mx = {-INFINITY, -INFINITY};

#pragma unroll 8
    for (int c = 0; c < CCH; ++c) {
        f2 v = xb[(size_t)c * (HW / 2)];
        ss += v * v;
        sm += v;
        mx.x = fmaxf(mx.x, v.x);
        mx.y = fmaxf(mx.y, v.y);
    }

    size_t o2 = (size_t)b * (HW / 2) + p2;
    const float inv = 1.0f / 64.0f;
    h4 mm = { (_Float16)mx.x, (_Float16)(sm.x * inv),
              (_Float16)mx.y, (_Float16)(sm.y * inv) };
    h2 l2v = { (_Float16)sqrtf(ss.x), (_Float16)sqrtf(ss.y) };
    reinterpret_cast<h4*>(mmp)[o2] = mm;           // 8 B store
    reinterpret_cast<h2*>(l2p)[o2] = l2v;          // 4 B store
}

// ---------------------------------------------------------------------------
// Kernel 2 (unchanged from R8): both branches + sum, 8 px/thread.
// Per conv row: h8 vector loads + 2 guarded edge scalars, reused across the
// 8 outputs. fp16 inputs; fp32 accumulate. NT output stores.
//
// local path index math (raw row-major reshape [B,4,256,256] -> [B,1,512,512]):
//   c = h>>7 ; hs = ((h&127)<<1)|(w>>8) ; ws = w&255
// tiles[b,i,y,x] = l2[b, (i>>1)*256 + y, (i&1)*256 + x], zero-padded in TILE
// space (guards on tile coords, NOT image coords).
// ---------------------------------------------------------------------------
__global__ __launch_bounds__(256) void attn_k(const _Float16* __restrict__ l2p,
                                              const h2* __restrict__ mmp,
                                              const float* __restrict__ lw,
                                              const float* __restrict__ lb,
                                              const float* __restrict__ gw,
                                              const float* __restrict__ gb,
                                              float* __restrict__ out) {
    __shared__ float s_lw[144];   // [4,4,3,3]
    __shared__ float s_lb[4];
    __shared__ float s_gw[18];    // [1,2,3,3]
    __shared__ float s_gb;

    int t = threadIdx.x;
    if (t < 144) s_lw[t] = lw[t];
    if (t < 4)   s_lb[t] = lb[t];
    if (t < 18)  s_gw[t] = gw[t];
    if (t == 0)  s_gb = gb[0];
    __syncthreads();

    int idx8 = blockIdx.x * 256 + t;   // 0 .. B*HW/8 - 1
    int b  = idx8 >> 15;               // HW/8 = 32768
    int p8 = idx8 & 32767;
    int h  = p8 >> 6;                  // 64 chunks of 8 px per row
    int w0 = (p8 & 63) << 3;           // 0..504, multiple of 8

    const _Float16* l2b = l2p + ((size_t)b << 18);
    const h2*       mmb = mmp + ((size_t)b << 18);

    // ---- global attention: 3x3 conv over (max, mean), relu, sigmoid ----
    float g[8];
#pragma unroll
    for (int j = 0; j < 8; ++j) g[j] = s_gb;
#pragma unroll
    for (int dh = -1; dh <= 1; ++dh) {
        int hh = h + dh;
        if ((unsigned)hh >= (unsigned)HH) continue;
        const h2* row = mmb + hh * WW + w0;
        h8 vA = *reinterpret_cast<const h8*>(row);       // px w0..w0+3
        h8 vB = *reinterpret_cast<const h8*>(row + 4);   // px w0+4..w0+7
        float m10[10], a10[10];
        if (w0 > 0) { h2 e = row[-1]; m10[0] = (float)e.x; a10[0] = (float)e.y; }
        else        { m10[0] = 0.f;   a10[0] = 0.f; }
#pragma unroll
        for (int j = 0; j < 4; ++j) {
            m10[1 + j] = (float)vA[2 * j];  a10[1 + j] = (float)vA[2 * j + 1];
            m10[5 + j] = (float)vB[2 * j];  a10[5 + j] = (float)vB[2 * j + 1];
        }
        if (w0 < WW - 8) { h2 e = row[8]; m10[9] = (float)e.x; a10[9] = (float)e.y; }
        else             { m10[9] = 0.f;  a10[9] = 0.f; }
#pragma unroll
        for (int k = 0; k < 3; ++k) {
            float wmk = s_gw[(dh + 1) * 3 + k];
            float wak = s_gw[9 + (dh + 1) * 3 + k];
#pragma unroll
            for (int j = 0; j < 8; ++j)
                g[j] = fmaf(m10[j + k], wmk, fmaf(a10[j + k], wak, g[j]));
        }
    }

    // ---- local attention: 3x3 conv (4 quadrant in-ch) in tile space ----
    int c   = h >> 7;
    int hs  = ((h & 127) << 1) | (w0 >> 8);
    int ws0 = w0 & 255;                // multiple of 8, 0..248

    float la[8];
#pragma unroll
    for (int j = 0; j < 8; ++j) la[j] = s_lb[c];
#pragma unroll
    for (int i = 0; i < 4; ++i) {
        const _Float16* base = l2b + (i >> 1) * (256 * WW) + (i & 1) * 256;
        const float* wi = s_lw + c * 36 + i * 9;
#pragma unroll
        for (int dh = -1; dh <= 1; ++dh) {
            int y = hs + dh;
            if ((unsigned)y >= 256u) continue;
            const _Float16* row = base + y * WW + ws0;
            h8 v = *reinterpret_cast<const h8*>(row);    // 16 B aligned
            float v10[10];
            v10[0] = (ws0 > 0)   ? (float)row[-1] : 0.f;
#pragma unroll
            for (int j = 0; j < 8; ++j) v10[1 + j] = (float)v[j];
            v10[9] = (ws0 < 248) ? (float)row[8]  : 0.f;
#pragma unroll
            for (int k = 0; k < 3; ++k) {
                float wk = wi[(dh + 1) * 3 + k];
#pragma unroll
                for (int j = 0; j < 8; ++j)
                    la[j] = fmaf(v10[j + k], wk, la[j]);
            }
        }
    }

    f4 oA, oB;
#pragma unroll
    for (int j = 0; j < 4; ++j) {
        oA[j] = 1.f / (1.f + __expf(-la[j]))
              + 1.f / (1.f + __expf(-fmaxf(g[j], 0.f)));
        oB[j] = 1.f / (1.f + __expf(-la[4 + j]))
              + 1.f / (1.f + __expf(-fmaxf(g[4 + j], 0.f)));
    }
    __builtin_nontemporal_store(oA, reinterpret_cast<f4*>(out) + idx8 * 2);
    __builtin_nontemporal_store(oB, reinterpret_cast<f4*>(out) + idx8 * 2 + 1);
}

extern "C" void kernel_launch(void* const* d_in, const int* in_sizes, int n_in,
                              void* d_out, int out_size, void* d_ws, size_t ws_size,
                              hipStream_t stream) {
    const float* x  = (const float*)d_in[0];   // [4,64,512,512]
    const float* lw = (const float*)d_in[1];   // [4,4,3,3]
    const float* lb = (const float*)d_in[2];   // [4]
    const float* gw = (const float*)d_in[3];   // [1,2,3,3]
    const float* gb = (const float*)d_in[4];   // [1]
    float* out = (float*)d_out;                // [4,1,512,512]

    h2*       mmp = (h2*)d_ws;                           // 4 MiB (max,mean)/px
    _Float16* l2p = (_Float16*)((char*)d_ws + (size_t)BB * HW * sizeof(h2));

    int n1 = BB * HW / 2;                      // 524288 threads, 2 px each
    reduce_k<<<n1 / 256, 256, 0, stream>>>(x, l2p, mmp);   // 2048 blocks

    int n2 = BB * HW / 8;                      // 131072 threads, 8 px each
    attn_k<<<n2 / 256, 256, 0, stream>>>(l2p, mmp, lw, lb, gw, gb, out);
}